// Round 8
// baseline (757.699 us; speedup 1.0000x reference)
//
#include <hip/hip_runtime.h>
#include <hip/hip_bf16.h>
#include <math.h>

#define N_NODES 10000
#define N_EDGES 320000
#define HEADS   4
#define CDIM    128
#define HC      512
#define LAYERS  4
#define DIN     7
#define EDIM    5

typedef short short8 __attribute__((ext_vector_type(8)));
typedef unsigned short us8 __attribute__((ext_vector_type(8)));
typedef float f32x4 __attribute__((ext_vector_type(4)));

__device__ __forceinline__ void atomAddF(float* p, float v) { unsafeAtomicAdd(p, v); }

__device__ __forceinline__ unsigned short f2bf(float f) {
  unsigned u = __float_as_uint(f);
  unsigned r = u + 0x7fffu + ((u >> 16) & 1u);
  return (unsigned short)(r >> 16);
}
__device__ __forceinline__ float bf2f(unsigned short u) {
  return __uint_as_float(((unsigned)u) << 16);
}

// ---------------- embed: h = relu(x @ embW + embB), fp32 + bf16 copies ----------------
__global__ __launch_bounds__(256) void embed_kernel(
    const float* __restrict__ x, const float* __restrict__ W,
    const float* __restrict__ b, float* __restrict__ h, unsigned short* __restrict__ hbf)
{
  int t = blockIdx.x * 256 + threadIdx.x;
  int n = t >> 7, c = t & 127;
  float acc = b[c];
#pragma unroll
  for (int k = 0; k < DIN; ++k) acc += x[n * DIN + k] * W[k * CDIM + c];
  acc = fmaxf(acc, 0.f);
  h[t] = acc;
  hbf[t] = f2bf(acc);
}

// ---------------- weight pack: bf16 + transpose (+ plain W2 copy) ----------------
__global__ __launch_bounds__(256) void pack_kernel(
    const float* __restrict__ Wl, const float* __restrict__ Wr,
    const float* __restrict__ W1, const float* __restrict__ W2,
    const float* __restrict__ gW, unsigned short* __restrict__ WlrT,
    unsigned short* __restrict__ W1T, unsigned short* __restrict__ W2T,
    unsigned short* __restrict__ gWT, unsigned short* __restrict__ W2bf)
{
  int t = blockIdx.x * 256 + threadIdx.x;
  if (t < 524288) {                       // 4*1024*128
    int k = t & 127, n = (t >> 7) & 1023, l = t >> 17;
    float v = (n < 512) ? Wl[(size_t)(l * 128 + k) * 512 + n]
                        : Wr[(size_t)(l * 128 + k) * 512 + (n - 512)];
    WlrT[t] = f2bf(v);
  } else if (t < 524288 + 32768) {        // 256*128
    int u = t - 524288; int k = u & 127, n = u >> 7;
    float v = (n < 128) ? W1[k * 128 + n] : W1[(128 + k) * 128 + (n - 128)];
    W1T[u] = f2bf(v);
  } else if (t < 557056 + 16384) {
    int u = t - 557056; int k = u & 127, n = u >> 7;
    W2T[u] = f2bf(W2[k * 128 + n]);
  } else if (t < 573440 + 16384) {
    int u = t - 573440; int k = u & 127, n = u >> 7;
    gWT[u] = f2bf(gW[k * 128 + n]);
  } else if (t < 589824 + 16384) {
    int u = t - 589824;
    W2bf[u] = f2bf(W2[u]);
  }
}

// ---------------- fused gate bias: gbF[n] = b2 @ gW + gb ----------------
__global__ __launch_bounds__(128) void fuse_bias_kernel(
    const float* __restrict__ b2, const float* __restrict__ gW,
    const float* __restrict__ gb, float* __restrict__ gbF)
{
  int n = threadIdx.x;
  float s = gb[n];
  for (int k = 0; k < 128; ++k) s += b2[k] * gW[k * 128 + n];
  gbF[n] = s;
}

// ---------------- degree histogram ----------------
__global__ __launch_bounds__(256) void hist_kernel(
    const int* __restrict__ ei, int* __restrict__ degD, int* __restrict__ degS)
{
  int e = blockIdx.x * 256 + threadIdx.x;
  if (e < N_EDGES) {
    atomicAdd(&degS[ei[e]], 1);
    atomicAdd(&degD[ei[N_EDGES + e]], 1);
  }
}

// ---------------- exclusive scan ----------------
__global__ __launch_bounds__(1024) void scan_kernel(
    const int* __restrict__ degD, int* __restrict__ offD, int* __restrict__ curD,
    const int* __restrict__ degS, int* __restrict__ offS, int* __restrict__ curS, int n)
{
  __shared__ int wsum[16];
  __shared__ int carry;
  int tid = threadIdx.x, wid = tid >> 6, lane = tid & 63;
  for (int arr = 0; arr < 2; ++arr) {
    const int* deg = arr ? degS : degD;
    int* off = arr ? offS : offD;
    int* cur = arr ? curS : curD;
    if (tid == 0) carry = 0;
    __syncthreads();
    for (int base = 0; base < n; base += 1024) {
      int i = base + tid;
      int v = (i < n) ? deg[i] : 0;
      int incl = v;
#pragma unroll
      for (int o = 1; o < 64; o <<= 1) {
        int t2 = __shfl_up(incl, o);
        if (lane >= o) incl += t2;
      }
      if (lane == 63) wsum[wid] = incl;
      __syncthreads();
      if (tid < 16) {
        int wv = wsum[tid];
#pragma unroll
        for (int o = 1; o < 16; o <<= 1) {
          int t2 = __shfl_up(wv, o);
          if (tid >= o) wv += t2;
        }
        wsum[tid] = wv;
      }
      __syncthreads();
      int woff = (wid > 0) ? wsum[wid - 1] : 0;
      int excl = carry + woff + incl - v;
      if (i < n) { off[i] = excl; cur[i] = excl; }
      __syncthreads();
      if (tid == 0) carry += wsum[15];
      __syncthreads();
    }
    if (tid == 0) off[n] = carry;
    __syncthreads();
  }
}

// ---------------- CSR scatter ----------------
__global__ __launch_bounds__(256) void scatter_kernel(
    const int* __restrict__ ei, int* __restrict__ curD, int* __restrict__ curS,
    int* __restrict__ eidD, int* __restrict__ eidS)
{
  int e = blockIdx.x * 256 + threadIdx.x;
  if (e < N_EDGES) {
    int s = ei[e], d = ei[N_EDGES + e];
    int p = atomicAdd(&curD[d], 1);
    eidD[p] = e;
    int q = atomicAdd(&curS[s], 1);
    eidS[q] = e;
  }
}

// ---------------- edge reorder into dst-CSR order (run once, reused 4x) --------------
__global__ __launch_bounds__(256) void reorder_kernel(
    const int* __restrict__ ei, const float* __restrict__ eattr,
    const int* __restrict__ eidD, int* __restrict__ esrc,
    float4* __restrict__ ea4, float* __restrict__ ea1)
{
  int idx = blockIdx.x * 256 + threadIdx.x;
  if (idx < N_EDGES) {
    int e = eidD[idx];
    esrc[idx] = ei[e];
    const float* p = &eattr[(size_t)e * 5];
    ea4[idx] = make_float4(p[0], p[1], p[2], p[3]);
    ea1[idx] = p[4];
  }
}

// ---------------- bf16 MFMA GEMM: C[M,N](bf16) = A[M,128] @ BT[N,128]^T ----
__global__ __launch_bounds__(256) void mfma_gemm_kernel(
    const unsigned short* __restrict__ A, const unsigned short* __restrict__ BT,
    unsigned short* __restrict__ C, int M, int ldc)
{
  __shared__ __align__(16) unsigned short sA[64 * 128];
  __shared__ __align__(16) unsigned short sB[64 * 128];
  int tid = threadIdx.x;
  int bm = blockIdx.y * 64, bn = blockIdx.x * 64;
#pragma unroll
  for (int i = 0; i < 4; ++i) {
    int ch = tid + i * 256;            // 1024 chunks of 16B
    int r = ch >> 4, kc = ch & 15;
    int gr = bm + r;
    short8 v = {0, 0, 0, 0, 0, 0, 0, 0};
    if (gr < M) v = *(const short8*)&A[(size_t)gr * 128 + kc * 8];
    *(short8*)&sA[r * 128 + ((kc ^ (r & 7)) * 8)] = v;
  }
#pragma unroll
  for (int i = 0; i < 4; ++i) {
    int ch = tid + i * 256;
    int r = ch >> 4, kc = ch & 15;
    short8 v = *(const short8*)&BT[(size_t)(bn + r) * 128 + kc * 8];
    *(short8*)&sB[r * 128 + ((kc ^ (r & 7)) * 8)] = v;
  }
  __syncthreads();
  int w = tid >> 6, lane = tid & 63;
  int wr = (w >> 1) * 32, wc = (w & 1) * 32;
  int l15 = lane & 15, q = lane >> 4;
  f32x4 acc00 = {0, 0, 0, 0}, acc01 = acc00, acc10 = acc00, acc11 = acc00;
#pragma unroll
  for (int ks = 0; ks < 4; ++ks) {
    int c0 = ks * 4 + q;
    int m0 = wr + l15, m1 = m0 + 16;
    int n0 = wc + l15, n1 = n0 + 16;
    short8 a0 = *(const short8*)&sA[m0 * 128 + ((c0 ^ (m0 & 7)) * 8)];
    short8 a1 = *(const short8*)&sA[m1 * 128 + ((c0 ^ (m1 & 7)) * 8)];
    short8 b0 = *(const short8*)&sB[n0 * 128 + ((c0 ^ (n0 & 7)) * 8)];
    short8 b1 = *(const short8*)&sB[n1 * 128 + ((c0 ^ (n1 & 7)) * 8)];
    acc00 = __builtin_amdgcn_mfma_f32_16x16x32_bf16(a0, b0, acc00, 0, 0, 0);
    acc01 = __builtin_amdgcn_mfma_f32_16x16x32_bf16(a0, b1, acc01, 0, 0, 0);
    acc10 = __builtin_amdgcn_mfma_f32_16x16x32_bf16(a1, b0, acc10, 0, 0, 0);
    acc11 = __builtin_amdgcn_mfma_f32_16x16x32_bf16(a1, b1, acc11, 0, 0, 0);
  }
#pragma unroll
  for (int mf = 0; mf < 2; ++mf) {
#pragma unroll
    for (int nf = 0; nf < 2; ++nf) {
      f32x4 acc = mf == 0 ? (nf == 0 ? acc00 : acc01) : (nf == 0 ? acc10 : acc11);
      int col = bn + wc + nf * 16 + l15;
#pragma unroll
      for (int r = 0; r < 4; ++r) {
        int row = bm + wr + mf * 16 + 4 * q + r;
        if (row < M) C[(size_t)row * ldc + col] = f2bf(acc[r]);
      }
    }
  }
}

// ---------------- GATv2 aggregation: 1 wave/node, zero LDS, pair-pipelined ----------
__global__ __launch_bounds__(256) void gat_agg_kernel(
    const float* __restrict__ h_in, float* __restrict__ h_out,
    unsigned short* __restrict__ hbf_out, const unsigned short* __restrict__ xlr,
    const int* __restrict__ esrc, const float4* __restrict__ ea4,
    const float* __restrict__ ea1, const int* __restrict__ offD,
    const float* __restrict__ We, const float* __restrict__ att,
    const float* __restrict__ gbias, const float* __restrict__ lng,
    const float* __restrict__ lnb)
{
  int tid = threadIdx.x;
  int w = tid >> 6, lane = tid & 63;
  int n = blockIdx.x * 4 + w;
  int base = lane * 8;

  float wWe[5][8];
#pragma unroll
  for (int k = 0; k < 5; ++k) {
    float4 a = *(const float4*)&We[k * HC + base];
    float4 b = *(const float4*)&We[k * HC + base + 4];
    wWe[k][0] = a.x; wWe[k][1] = a.y; wWe[k][2] = a.z; wWe[k][3] = a.w;
    wWe[k][4] = b.x; wWe[k][5] = b.y; wWe[k][6] = b.z; wWe[k][7] = b.w;
  }
  float wAtt[8];
  {
    float4 a = *(const float4*)&att[base];
    float4 b = *(const float4*)&att[base + 4];
    wAtt[0] = a.x; wAtt[1] = a.y; wAtt[2] = a.z; wAtt[3] = a.w;
    wAtt[4] = b.x; wAtt[5] = b.y; wAtt[6] = b.z; wAtt[7] = b.w;
  }
  float xr_reg[8];
  {
    us8 u = *(const us8*)&xlr[(size_t)n * 1024 + 512 + base];
#pragma unroll
    for (int j = 0; j < 8; ++j) xr_reg[j] = bf2f(u[j]);
  }

  int e0 = offD[n], e1 = offD[n + 1];
  float m = -INFINITY, dsum = 0.f;
  float acc[8] = {0.f, 0.f, 0.f, 0.f, 0.f, 0.f, 0.f, 0.f};

  us8 uA = {0, 0, 0, 0, 0, 0, 0, 0}, uB = uA;
  float4 qaA = {0, 0, 0, 0}, qaB = {0, 0, 0, 0};
  float qeA = 0.f, qeB = 0.f;
  int sA1 = 0, sB1 = 0;

  if (e0 < e1) {
    int iB = (e0 + 1 < e1) ? e0 + 1 : e0;
    int sA0 = esrc[e0], sB0 = esrc[iB];
    uA = *(const us8*)&xlr[(size_t)sA0 * 1024 + base];
    uB = *(const us8*)&xlr[(size_t)sB0 * 1024 + base];
    qaA = ea4[e0]; qeA = ea1[e0];
    qaB = ea4[iB]; qeB = ea1[iB];
    int jA = (e0 + 2 < e1) ? e0 + 2 : e0;
    int jB = (e0 + 3 < e1) ? e0 + 3 : e0;
    sA1 = esrc[jA]; sB1 = esrc[jB];
  }

  for (int i = e0; i < e1; i += 2) {
    float x0[8], x1[8];
#pragma unroll
    for (int j = 0; j < 8; ++j) { x0[j] = bf2f(uA[j]); x1[j] = bf2f(uB[j]); }
    float a0 = qaA.x, a1 = qaA.y, a2 = qaA.z, a3 = qaA.w, a4 = qeA;
    float b0 = qaB.x, b1 = qaB.y, b2 = qaB.z, b3 = qaB.w, b4 = qeB;

    uA = *(const us8*)&xlr[(size_t)sA1 * 1024 + base];
    uB = *(const us8*)&xlr[(size_t)sB1 * 1024 + base];
    {
      int jA = (i + 2 < e1) ? i + 2 : e0;
      int jB = (i + 3 < e1) ? i + 3 : e0;
      qaA = ea4[jA]; qeA = ea1[jA];
      qaB = ea4[jB]; qeB = ea1[jB];
      int kA = (i + 4 < e1) ? i + 4 : e0;
      int kB = (i + 5 < e1) ? i + 5 : e0;
      sA1 = esrc[kA]; sB1 = esrc[kB];
    }

    float lg0 = 0.f, lg1 = 0.f;
#pragma unroll
    for (int j = 0; j < 8; ++j) {
      float v0 = x0[j] + xr_reg[j] + a0 * wWe[0][j] + a1 * wWe[1][j]
               + a2 * wWe[2][j] + a3 * wWe[3][j] + a4 * wWe[4][j];
      v0 = (v0 > 0.f) ? v0 : 0.2f * v0;
      lg0 += v0 * wAtt[j];
      float v1 = x1[j] + xr_reg[j] + b0 * wWe[0][j] + b1 * wWe[1][j]
               + b2 * wWe[2][j] + b3 * wWe[3][j] + b4 * wWe[4][j];
      v1 = (v1 > 0.f) ? v1 : 0.2f * v1;
      lg1 += v1 * wAtt[j];
    }
    lg0 += __shfl_xor(lg0, 1); lg1 += __shfl_xor(lg1, 1);
    lg0 += __shfl_xor(lg0, 2); lg1 += __shfl_xor(lg1, 2);
    lg0 += __shfl_xor(lg0, 4); lg1 += __shfl_xor(lg1, 4);
    lg0 += __shfl_xor(lg0, 8); lg1 += __shfl_xor(lg1, 8);
    lg1 = (i + 1 < e1) ? lg1 : -INFINITY;

    float nm = fmaxf(m, fmaxf(lg0, lg1));
    float sc = __expf(m - nm);
    float p0 = __expf(lg0 - nm);
    float p1 = __expf(lg1 - nm);
    dsum = dsum * sc + p0 + p1;
#pragma unroll
    for (int j = 0; j < 8; ++j) acc[j] = (acc[j] * sc + p0 * x0[j]) + p1 * x1[j];
    m = nm;
  }

  float inv = (dsum > 0.f) ? (1.f / dsum) : 0.f;
  int c8 = (lane & 15) * 8;
  float o[8];
  float s1 = 0.f, s2 = 0.f;
#pragma unroll
  for (int j = 0; j < 8; ++j) {
    float v = acc[j] * inv;
    v += __shfl_xor(v, 16);
    v += __shfl_xor(v, 32);
    float oo = 0.25f * v + gbias[c8 + j];
    oo = fmaxf(oo, 0.f);
    oo += h_in[(size_t)n * 128 + c8 + j];
    o[j] = oo;
    s1 += oo; s2 += oo * oo;
  }
  s1 += __shfl_xor(s1, 1);  s2 += __shfl_xor(s2, 1);
  s1 += __shfl_xor(s1, 2);  s2 += __shfl_xor(s2, 2);
  s1 += __shfl_xor(s1, 4);  s2 += __shfl_xor(s2, 4);
  s1 += __shfl_xor(s1, 8);  s2 += __shfl_xor(s2, 8);
  s1 += __shfl_xor(s1, 16); s2 += __shfl_xor(s2, 16);
  s1 += __shfl_xor(s1, 32); s2 += __shfl_xor(s2, 32);
  float mean = s1 * (1.f / 512.f);
  float var = s2 * (1.f / 512.f) - mean * mean;
  float rs = rsqrtf(var + 1e-5f);
  if (lane < 16) {
#pragma unroll
    for (int j = 0; j < 8; ++j) {
      float val = (o[j] - mean) * rs * lng[c8 + j] + lnb[c8 + j];
      h_out[(size_t)n * 128 + c8 + j] = val;
      hbf_out[(size_t)n * 128 + c8 + j] = f2bf(val);
    }
  }
}

// ---------------- social pool edge kernel: fused-weight, reg-B, reg-scatter --------
// 512 thr = 8 waves; wave w owns output cols 16w..16w+15. T tile in LDS only.
// inter = T@W2 + b2 ; g = T@F + gbF (F = W2@gW precomputed) ; gated = inter*sigmoid(g)
__global__ __launch_bounds__(512) void sp_edge_kernel(
    const unsigned short* __restrict__ sab, const float* __restrict__ b1,
    const unsigned short* __restrict__ W2T, const float* __restrict__ b2,
    const unsigned short* __restrict__ FT, const float* __restrict__ gbF,
    const int* __restrict__ ei, const int* __restrict__ eidS,
    float* __restrict__ pool)
{
  __shared__ __align__(16) unsigned short sT[64 * 128];   // 16KB, swizzled
  __shared__ int rsrc[64];
  __shared__ int rdst[64];
  int tid = threadIdx.x;
  int w = tid >> 6, lane = tid & 63;
  int l15 = lane & 15, q = lane >> 4;
  int col = w * 16 + l15;

  // tile-invariant B fragments in registers (both GEMMs)
  short8 bW[4], bF[4];
#pragma unroll
  for (int ks = 0; ks < 4; ++ks) {
    bW[ks] = *(const short8*)&W2T[(size_t)col * 128 + (ks * 4 + q) * 8];
    bF[ks] = *(const short8*)&FT [(size_t)col * 128 + (ks * 4 + q) * 8];
  }
  float b2c = b2[col];
  float gbc = gbF[col];

  int ebase = blockIdx.x * 64;          // 5000*64 == N_EDGES exactly: no partial tiles
  if (tid < 64) {
    int e = eidS[ebase + tid];
    rsrc[tid] = ei[e];
    rdst[tid] = ei[N_EDGES + e];
  }
  __syncthreads();

  // build T tile: 1024 chunks / 512 threads
#pragma unroll
  for (int i = 0; i < 2; ++i) {
    int ch = tid + i * 512;
    int r = ch >> 4, kc = ch & 15, c0 = kc * 8;
    int s = rsrc[r], d = rdst[r];
    us8 ua = *(const us8*)&sab[(size_t)s * 256 + c0];
    us8 ub = *(const us8*)&sab[(size_t)d * 256 + 128 + c0];
    float4 bb0 = *(const float4*)&b1[c0];
    float4 bb1 = *(const float4*)&b1[c0 + 4];
    float bv[8] = {bb0.x, bb0.y, bb0.z, bb0.w, bb1.x, bb1.y, bb1.z, bb1.w};
    short8 o;
#pragma unroll
    for (int j = 0; j < 8; ++j)
      o[j] = (short)f2bf(fmaxf(bf2f(ua[j]) + bf2f(ub[j]) + bv[j], 0.f));
    *(short8*)&sT[r * 128 + ((kc ^ (r & 7)) * 8)] = o;
  }
  __syncthreads();

#pragma unroll
  for (int rg = 0; rg < 4; ++rg) {
    int m = rg * 16 + l15;
    f32x4 acc1 = {0, 0, 0, 0}, acc2 = {0, 0, 0, 0};
#pragma unroll
    for (int ks = 0; ks < 4; ++ks) {
      short8 a = *(const short8*)&sT[m * 128 + (((ks * 4 + q) ^ (m & 7)) * 8)];
      acc1 = __builtin_amdgcn_mfma_f32_16x16x32_bf16(a, bW[ks], acc1, 0, 0, 0);
      acc2 = __builtin_amdgcn_mfma_f32_16x16x32_bf16(a, bF[ks], acc2, 0, 0, 0);
    }
    // gate + run-merged scatter over this lane's 4 rows
    int rb = rg * 16 + 4 * q;
    float g[4];
#pragma unroll
    for (int r = 0; r < 4; ++r) {
      float inter = acc1[r] + b2c;
      float gg = acc2[r] + gbc;
      g[r] = inter * (1.f / (1.f + __expf(-gg)));
    }
    int s0 = rsrc[rb], s1 = rsrc[rb + 1], s2 = rsrc[rb + 2], s3 = rsrc[rb + 3];
    float run = g[0]; int cur = s0;
    if (s1 == cur) run += g[1];
    else { atomAddF(&pool[(size_t)cur * 128 + col], run); cur = s1; run = g[1]; }
    if (s2 == cur) run += g[2];
    else { atomAddF(&pool[(size_t)cur * 128 + col], run); cur = s2; run = g[2]; }
    if (s3 == cur) run += g[3];
    else { atomAddF(&pool[(size_t)cur * 128 + col], run); cur = s3; run = g[3]; }
    atomAddF(&pool[(size_t)cur * 128 + col], run);
  }
}

// ---------------- finalize: out = LN(h + pool/max(cnt,1)) ----------------
__global__ __launch_bounds__(256) void finalize_kernel(
    const float* __restrict__ h, const float* __restrict__ pool,
    const int* __restrict__ degS, const float* __restrict__ g,
    const float* __restrict__ b, float* __restrict__ out)
{
  int t = blockIdx.x * 256 + threadIdx.x;
  int n = t >> 6, lane = t & 63;
  if (n >= N_NODES) return;
  float cnt = fmaxf((float)degS[n], 1.f);
  float a = h[(size_t)n * 128 + lane] + pool[(size_t)n * 128 + lane] / cnt;
  float c2 = h[(size_t)n * 128 + 64 + lane] + pool[(size_t)n * 128 + 64 + lane] / cnt;
  float s = a + c2, s2 = a * a + c2 * c2;
#pragma unroll
  for (int o = 1; o < 64; o <<= 1) { s += __shfl_xor(s, o); s2 += __shfl_xor(s2, o); }
  float mean = s * (1.f / 128.f);
  float var = s2 * (1.f / 128.f) - mean * mean;
  float rs = rsqrtf(var + 1e-5f);
  out[(size_t)n * 128 + lane] = (a - mean) * rs * g[lane] + b[lane];
  out[(size_t)n * 128 + 64 + lane] = (c2 - mean) * rs * g[64 + lane] + b[64 + lane];
}

// ---------------- host ----------------
extern "C" void kernel_launch(void* const* d_in, const int* in_sizes, int n_in,
                              void* d_out, int out_size, void* d_ws, size_t ws_size,
                              hipStream_t stream) {
  (void)in_sizes; (void)n_in; (void)out_size; (void)ws_size;
  const float* x     = (const float*)d_in[0];
  const int*   ei    = (const int*)d_in[1];
  const float* eattr = (const float*)d_in[2];
  const float* embW  = (const float*)d_in[3];
  const float* embB  = (const float*)d_in[4];
  const float* gWl   = (const float*)d_in[5];
  const float* gWr   = (const float*)d_in[6];
  const float* gWe   = (const float*)d_in[7];
  const float* gAtt  = (const float*)d_in[8];
  const float* gB    = (const float*)d_in[9];
  const float* lnG   = (const float*)d_in[10];
  const float* lnB   = (const float*)d_in[11];
  const float* spW1  = (const float*)d_in[12];
  const float* spB1  = (const float*)d_in[13];
  const float* spW2  = (const float*)d_in[14];
  const float* spB2  = (const float*)d_in[15];
  const float* spGW  = (const float*)d_in[16];
  const float* spGB  = (const float*)d_in[17];
  const float* fnG   = (const float*)d_in[18];
  const float* fnB   = (const float*)d_in[19];
  float* out = (float*)d_out;

  char* ws = (char*)d_ws;
  size_t off = 0;
  auto alloc = [&](size_t bytes) {
    void* p = ws + off;
    off = (off + bytes + 255) & ~(size_t)255;
    return p;
  };
  float* hA   = (float*)alloc((size_t)N_NODES * 128 * 4);
  float* hB   = (float*)alloc((size_t)N_NODES * 128 * 4);
  unsigned short* hbfA = (unsigned short*)alloc((size_t)N_NODES * 128 * 2);
  unsigned short* hbfB = (unsigned short*)alloc((size_t)N_NODES * 128 * 2);
  unsigned short* xlr  = (unsigned short*)alloc((size_t)N_NODES * 1024 * 2);
  unsigned short* sab  = (unsigned short*)alloc((size_t)N_NODES * 256 * 2);
  float* pool = (float*)alloc((size_t)N_NODES * 128 * 4);
  unsigned short* WlrT = (unsigned short*)alloc((size_t)4 * 1024 * 128 * 2);
  unsigned short* W1T  = (unsigned short*)alloc((size_t)256 * 128 * 2);
  unsigned short* W2T  = (unsigned short*)alloc((size_t)128 * 128 * 2);
  unsigned short* gWT  = (unsigned short*)alloc((size_t)128 * 128 * 2);
  unsigned short* W2bf = (unsigned short*)alloc((size_t)128 * 128 * 2);
  unsigned short* FT   = (unsigned short*)alloc((size_t)128 * 128 * 2);
  float* gbF = (float*)alloc((size_t)128 * 4);
  int* degD = (int*)alloc((size_t)N_NODES * 4);
  int* degS = (int*)alloc((size_t)N_NODES * 4);
  int* offD = (int*)alloc((size_t)(N_NODES + 1) * 4);
  int* offS = (int*)alloc((size_t)(N_NODES + 1) * 4);
  int* curD = (int*)alloc((size_t)N_NODES * 4);
  int* curS = (int*)alloc((size_t)N_NODES * 4);
  int* eidD = (int*)alloc((size_t)N_EDGES * 4);
  int* eidS = (int*)alloc((size_t)N_EDGES * 4);
  int* esrc = (int*)alloc((size_t)N_EDGES * 4);
  float4* ea4 = (float4*)alloc((size_t)N_EDGES * 16);
  float* ea1 = (float*)alloc((size_t)N_EDGES * 4);

  hipMemsetAsync(degD, 0, (size_t)N_NODES * 4, stream);
  hipMemsetAsync(degS, 0, (size_t)N_NODES * 4, stream);
  hipMemsetAsync(pool, 0, (size_t)N_NODES * 128 * 4, stream);

  pack_kernel<<<(606208 + 255) / 256, 256, 0, stream>>>(gWl, gWr, spW1, spW2, spGW,
                                                        WlrT, W1T, W2T, gWT, W2bf);
  // F^T = (W2 @ gW)^T  via  C[n][k] = sum_j gWT[n][j] * W2bf[k][j]
  mfma_gemm_kernel<<<dim3(2, 2), 256, 0, stream>>>(gWT, W2bf, FT, 128, 128);
  fuse_bias_kernel<<<1, 128, 0, stream>>>(spB2, spGW, spGB, gbF);

  embed_kernel<<<(N_NODES * 128) / 256, 256, 0, stream>>>(x, embW, embB, hA, hbfA);
  hist_kernel<<<(N_EDGES + 255) / 256, 256, 0, stream>>>(ei, degD, degS);
  scan_kernel<<<1, 1024, 0, stream>>>(degD, offD, curD, degS, offS, curS, N_NODES);
  scatter_kernel<<<(N_EDGES + 255) / 256, 256, 0, stream>>>(ei, curD, curS, eidD, eidS);
  reorder_kernel<<<(N_EDGES + 255) / 256, 256, 0, stream>>>(ei, eattr, eidD, esrc, ea4, ea1);

  const int MB64 = (N_NODES + 63) / 64;   // 157
  float* hcur = hA; float* hnext = hB;
  unsigned short* hbcur = hbfA; unsigned short* hbnext = hbfB;
  for (int l = 0; l < LAYERS; ++l) {
    mfma_gemm_kernel<<<dim3(16, MB64), 256, 0, stream>>>(
        hbcur, WlrT + (size_t)l * 1024 * 128, xlr, N_NODES, 1024);
    gat_agg_kernel<<<(N_NODES + 3) / 4, 256, 0, stream>>>(hcur, hnext, hbnext, xlr,
                                                          esrc, ea4, ea1, offD,
                                                          gWe + (size_t)l * EDIM * HC,
                                                          gAtt + (size_t)l * HC,
                                                          gB + (size_t)l * 128,
                                                          lnG + (size_t)l * 128,
                                                          lnB + (size_t)l * 128);
    float* t1 = hcur; hcur = hnext; hnext = t1;
    unsigned short* t2 = hbcur; hbcur = hbnext; hbnext = t2;
  }
  mfma_gemm_kernel<<<dim3(4, MB64), 256, 0, stream>>>(hbcur, W1T, sab, N_NODES, 256);
  sp_edge_kernel<<<N_EDGES / 64, 512, 0, stream>>>(sab, spB1, W2T, spB2, FT, gbF,
                                                   ei, eidS, pool);
  finalize_kernel<<<(N_NODES + 3) / 4, 256, 0, stream>>>(hcur, pool, degS, fnG, fnB, out);
}

// Round 9
// 721.203 us; speedup vs baseline: 1.0506x; 1.0506x over previous
//
#include <hip/hip_runtime.h>
#include <hip/hip_bf16.h>
#include <math.h>

#define N_NODES 10000
#define N_EDGES 320000
#define HEADS   4
#define CDIM    128
#define HC      512
#define LAYERS  4
#define DIN     7
#define EDIM    5

typedef short short8 __attribute__((ext_vector_type(8)));
typedef unsigned short us8 __attribute__((ext_vector_type(8)));
typedef float f32x4 __attribute__((ext_vector_type(4)));

__device__ __forceinline__ void atomAddF(float* p, float v) { unsafeAtomicAdd(p, v); }

__device__ __forceinline__ unsigned short f2bf(float f) {
  unsigned u = __float_as_uint(f);
  unsigned r = u + 0x7fffu + ((u >> 16) & 1u);
  return (unsigned short)(r >> 16);
}
__device__ __forceinline__ float bf2f(unsigned short u) {
  return __uint_as_float(((unsigned)u) << 16);
}

// ---------------- embed: h = relu(x @ embW + embB), fp32 + bf16 copies ----------------
__global__ __launch_bounds__(256) void embed_kernel(
    const float* __restrict__ x, const float* __restrict__ W,
    const float* __restrict__ b, float* __restrict__ h, unsigned short* __restrict__ hbf)
{
  int t = blockIdx.x * 256 + threadIdx.x;
  int n = t >> 7, c = t & 127;
  float acc = b[c];
#pragma unroll
  for (int k = 0; k < DIN; ++k) acc += x[n * DIN + k] * W[k * CDIM + c];
  acc = fmaxf(acc, 0.f);
  h[t] = acc;
  hbf[t] = f2bf(acc);
}

// ---------------- weight pack: bf16 + transpose (+ plain W2 copy) ----------------
__global__ __launch_bounds__(256) void pack_kernel(
    const float* __restrict__ Wl, const float* __restrict__ Wr,
    const float* __restrict__ W1, const float* __restrict__ W2,
    const float* __restrict__ gW, unsigned short* __restrict__ WlrT,
    unsigned short* __restrict__ W1T, unsigned short* __restrict__ W2T,
    unsigned short* __restrict__ gWT, unsigned short* __restrict__ W2bf)
{
  int t = blockIdx.x * 256 + threadIdx.x;
  if (t < 524288) {                       // 4*1024*128
    int k = t & 127, n = (t >> 7) & 1023, l = t >> 17;
    float v = (n < 512) ? Wl[(size_t)(l * 128 + k) * 512 + n]
                        : Wr[(size_t)(l * 128 + k) * 512 + (n - 512)];
    WlrT[t] = f2bf(v);
  } else if (t < 524288 + 32768) {        // 256*128
    int u = t - 524288; int k = u & 127, n = u >> 7;
    float v = (n < 128) ? W1[k * 128 + n] : W1[(128 + k) * 128 + (n - 128)];
    W1T[u] = f2bf(v);
  } else if (t < 557056 + 16384) {
    int u = t - 557056; int k = u & 127, n = u >> 7;
    W2T[u] = f2bf(W2[k * 128 + n]);
  } else if (t < 573440 + 16384) {
    int u = t - 573440; int k = u & 127, n = u >> 7;
    gWT[u] = f2bf(gW[k * 128 + n]);
  } else if (t < 589824 + 16384) {
    int u = t - 589824;
    W2bf[u] = f2bf(W2[u]);
  }
}

// ---------------- fused gate bias: gbF[n] = b2 @ gW + gb ----------------
__global__ __launch_bounds__(128) void fuse_bias_kernel(
    const float* __restrict__ b2, const float* __restrict__ gW,
    const float* __restrict__ gb, float* __restrict__ gbF)
{
  int n = threadIdx.x;
  float s = gb[n];
  for (int k = 0; k < 128; ++k) s += b2[k] * gW[k * 128 + n];
  gbF[n] = s;
}

// ---------------- degree histogram ----------------
__global__ __launch_bounds__(256) void hist_kernel(
    const int* __restrict__ ei, int* __restrict__ degD, int* __restrict__ degS)
{
  int e = blockIdx.x * 256 + threadIdx.x;
  if (e < N_EDGES) {
    atomicAdd(&degS[ei[e]], 1);
    atomicAdd(&degD[ei[N_EDGES + e]], 1);
  }
}

// ---------------- exclusive scan ----------------
__global__ __launch_bounds__(1024) void scan_kernel(
    const int* __restrict__ degD, int* __restrict__ offD, int* __restrict__ curD,
    const int* __restrict__ degS, int* __restrict__ offS, int* __restrict__ curS, int n)
{
  __shared__ int wsum[16];
  __shared__ int carry;
  int tid = threadIdx.x, wid = tid >> 6, lane = tid & 63;
  for (int arr = 0; arr < 2; ++arr) {
    const int* deg = arr ? degS : degD;
    int* off = arr ? offS : offD;
    int* cur = arr ? curS : curD;
    if (tid == 0) carry = 0;
    __syncthreads();
    for (int base = 0; base < n; base += 1024) {
      int i = base + tid;
      int v = (i < n) ? deg[i] : 0;
      int incl = v;
#pragma unroll
      for (int o = 1; o < 64; o <<= 1) {
        int t2 = __shfl_up(incl, o);
        if (lane >= o) incl += t2;
      }
      if (lane == 63) wsum[wid] = incl;
      __syncthreads();
      if (tid < 16) {
        int wv = wsum[tid];
#pragma unroll
        for (int o = 1; o < 16; o <<= 1) {
          int t2 = __shfl_up(wv, o);
          if (tid >= o) wv += t2;
        }
        wsum[tid] = wv;
      }
      __syncthreads();
      int woff = (wid > 0) ? wsum[wid - 1] : 0;
      int excl = carry + woff + incl - v;
      if (i < n) { off[i] = excl; cur[i] = excl; }
      __syncthreads();
      if (tid == 0) carry += wsum[15];
      __syncthreads();
    }
    if (tid == 0) off[n] = carry;
    __syncthreads();
  }
}

// ---------------- CSR scatter ----------------
__global__ __launch_bounds__(256) void scatter_kernel(
    const int* __restrict__ ei, int* __restrict__ curD, int* __restrict__ curS,
    int* __restrict__ eidD, int* __restrict__ eidS)
{
  int e = blockIdx.x * 256 + threadIdx.x;
  if (e < N_EDGES) {
    int s = ei[e], d = ei[N_EDGES + e];
    int p = atomicAdd(&curD[d], 1);
    eidD[p] = e;
    int q = atomicAdd(&curS[s], 1);
    eidS[q] = e;
  }
}

// ---------------- edge reorder into dst-CSR order (run once, reused 4x) --------------
__global__ __launch_bounds__(256) void reorder_kernel(
    const int* __restrict__ ei, const float* __restrict__ eattr,
    const int* __restrict__ eidD, int* __restrict__ esrc,
    float4* __restrict__ ea4, float* __restrict__ ea1)
{
  int idx = blockIdx.x * 256 + threadIdx.x;
  if (idx < N_EDGES) {
    int e = eidD[idx];
    esrc[idx] = ei[e];
    const float* p = &eattr[(size_t)e * 5];
    ea4[idx] = make_float4(p[0], p[1], p[2], p[3]);
    ea1[idx] = p[4];
  }
}

// ---------------- bf16 MFMA GEMM: C[M,N](bf16) = A[M,128] @ BT[N,128]^T ----
__global__ __launch_bounds__(256) void mfma_gemm_kernel(
    const unsigned short* __restrict__ A, const unsigned short* __restrict__ BT,
    unsigned short* __restrict__ C, int M, int ldc)
{
  __shared__ __align__(16) unsigned short sA[64 * 128];
  __shared__ __align__(16) unsigned short sB[64 * 128];
  int tid = threadIdx.x;
  int bm = blockIdx.y * 64, bn = blockIdx.x * 64;
#pragma unroll
  for (int i = 0; i < 4; ++i) {
    int ch = tid + i * 256;            // 1024 chunks of 16B
    int r = ch >> 4, kc = ch & 15;
    int gr = bm + r;
    short8 v = {0, 0, 0, 0, 0, 0, 0, 0};
    if (gr < M) v = *(const short8*)&A[(size_t)gr * 128 + kc * 8];
    *(short8*)&sA[r * 128 + ((kc ^ (r & 7)) * 8)] = v;
  }
#pragma unroll
  for (int i = 0; i < 4; ++i) {
    int ch = tid + i * 256;
    int r = ch >> 4, kc = ch & 15;
    short8 v = *(const short8*)&BT[(size_t)(bn + r) * 128 + kc * 8];
    *(short8*)&sB[r * 128 + ((kc ^ (r & 7)) * 8)] = v;
  }
  __syncthreads();
  int w = tid >> 6, lane = tid & 63;
  int wr = (w >> 1) * 32, wc = (w & 1) * 32;
  int l15 = lane & 15, q = lane >> 4;
  f32x4 acc00 = {0, 0, 0, 0}, acc01 = acc00, acc10 = acc00, acc11 = acc00;
#pragma unroll
  for (int ks = 0; ks < 4; ++ks) {
    int c0 = ks * 4 + q;
    int m0 = wr + l15, m1 = m0 + 16;
    int n0 = wc + l15, n1 = n0 + 16;
    short8 a0 = *(const short8*)&sA[m0 * 128 + ((c0 ^ (m0 & 7)) * 8)];
    short8 a1 = *(const short8*)&sA[m1 * 128 + ((c0 ^ (m1 & 7)) * 8)];
    short8 b0 = *(const short8*)&sB[n0 * 128 + ((c0 ^ (n0 & 7)) * 8)];
    short8 b1 = *(const short8*)&sB[n1 * 128 + ((c0 ^ (n1 & 7)) * 8)];
    acc00 = __builtin_amdgcn_mfma_f32_16x16x32_bf16(a0, b0, acc00, 0, 0, 0);
    acc01 = __builtin_amdgcn_mfma_f32_16x16x32_bf16(a0, b1, acc01, 0, 0, 0);
    acc10 = __builtin_amdgcn_mfma_f32_16x16x32_bf16(a1, b0, acc10, 0, 0, 0);
    acc11 = __builtin_amdgcn_mfma_f32_16x16x32_bf16(a1, b1, acc11, 0, 0, 0);
  }
#pragma unroll
  for (int mf = 0; mf < 2; ++mf) {
#pragma unroll
    for (int nf = 0; nf < 2; ++nf) {
      f32x4 acc = mf == 0 ? (nf == 0 ? acc00 : acc01) : (nf == 0 ? acc10 : acc11);
      int col = bn + wc + nf * 16 + l15;
#pragma unroll
      for (int r = 0; r < 4; ++r) {
        int row = bm + wr + mf * 16 + 4 * q + r;
        if (row < M) C[(size_t)row * ldc + col] = f2bf(acc[r]);
      }
    }
  }
}

// ---------------- GATv2 aggregation: 1 wave/node, zero LDS, 2-pair-deep pipeline ----
// lane owns 8 of 512 (h,c); 16-lane group = 1 head. Weights in VGPRs.
// 4 edges per loop iter in two stages; payload loads issued 2 stages ahead.
__global__ __launch_bounds__(256) void gat_agg_kernel(
    const float* __restrict__ h_in, float* __restrict__ h_out,
    unsigned short* __restrict__ hbf_out, const unsigned short* __restrict__ xlr,
    const int* __restrict__ esrc, const float4* __restrict__ ea4,
    const float* __restrict__ ea1, const int* __restrict__ offD,
    const float* __restrict__ We, const float* __restrict__ att,
    const float* __restrict__ gbias, const float* __restrict__ lng,
    const float* __restrict__ lnb)
{
  int tid = threadIdx.x;
  int w = tid >> 6, lane = tid & 63;
  int n = blockIdx.x * 4 + w;
  int base = lane * 8;

  float wWe[5][8];
#pragma unroll
  for (int k = 0; k < 5; ++k) {
    float4 a = *(const float4*)&We[k * HC + base];
    float4 b = *(const float4*)&We[k * HC + base + 4];
    wWe[k][0] = a.x; wWe[k][1] = a.y; wWe[k][2] = a.z; wWe[k][3] = a.w;
    wWe[k][4] = b.x; wWe[k][5] = b.y; wWe[k][6] = b.z; wWe[k][7] = b.w;
  }
  float wAtt[8];
  {
    float4 a = *(const float4*)&att[base];
    float4 b = *(const float4*)&att[base + 4];
    wAtt[0] = a.x; wAtt[1] = a.y; wAtt[2] = a.z; wAtt[3] = a.w;
    wAtt[4] = b.x; wAtt[5] = b.y; wAtt[6] = b.z; wAtt[7] = b.w;
  }
  float xr_reg[8];
  {
    us8 u = *(const us8*)&xlr[(size_t)n * 1024 + 512 + base];
#pragma unroll
    for (int j = 0; j < 8; ++j) xr_reg[j] = bf2f(u[j]);
  }

  int e0 = offD[n], e1 = offD[n + 1];
  float m = -INFINITY, dsum = 0.f;
  float acc[8] = {0.f, 0.f, 0.f, 0.f, 0.f, 0.f, 0.f, 0.f};

  if (e0 < e1) {
    int last = e1 - 1;
    int ib = (e0 + 1 < e1) ? e0 + 1 : last;
    int ic = (e0 + 2 < e1) ? e0 + 2 : last;
    int id2 = (e0 + 3 < e1) ? e0 + 3 : last;
    us8 uA = *(const us8*)&xlr[(size_t)esrc[e0] * 1024 + base];
    us8 uB = *(const us8*)&xlr[(size_t)esrc[ib] * 1024 + base];
    us8 uC = *(const us8*)&xlr[(size_t)esrc[ic] * 1024 + base];
    us8 uD = *(const us8*)&xlr[(size_t)esrc[id2] * 1024 + base];
    float4 qaA = ea4[e0]; float qeA = ea1[e0];
    float4 qaB = ea4[ib]; float qeB = ea1[ib];
    int j4 = (e0 + 4 < e1) ? e0 + 4 : last;
    int j5 = (e0 + 5 < e1) ? e0 + 5 : last;
    int sN0 = esrc[j4], sN1 = esrc[j5];

    for (int i = e0; i < e1; i += 4) {
      // ===== stage 1: edges i, i+1 =====
      float x0[8], x1[8];
#pragma unroll
      for (int j = 0; j < 8; ++j) { x0[j] = bf2f(uA[j]); x1[j] = bf2f(uB[j]); }
      uA = *(const us8*)&xlr[(size_t)sN0 * 1024 + base];   // payload i+4
      uB = *(const us8*)&xlr[(size_t)sN1 * 1024 + base];   // payload i+5
      int j2 = (i + 2 < e1) ? i + 2 : last;
      int j3 = (i + 3 < e1) ? i + 3 : last;
      float4 qaC = ea4[j2]; float qeC = ea1[j2];
      float4 qaD = ea4[j3]; float qeD = ea1[j3];
      int j6 = (i + 6 < e1) ? i + 6 : last;
      int j7 = (i + 7 < e1) ? i + 7 : last;
      int sN2 = esrc[j6], sN3 = esrc[j7];

      float lg0 = 0.f, lg1 = 0.f;
#pragma unroll
      for (int j = 0; j < 8; ++j) {
        float v0 = x0[j] + xr_reg[j] + qaA.x * wWe[0][j] + qaA.y * wWe[1][j]
                 + qaA.z * wWe[2][j] + qaA.w * wWe[3][j] + qeA * wWe[4][j];
        v0 = (v0 > 0.f) ? v0 : 0.2f * v0;
        lg0 += v0 * wAtt[j];
        float v1 = x1[j] + xr_reg[j] + qaB.x * wWe[0][j] + qaB.y * wWe[1][j]
                 + qaB.z * wWe[2][j] + qaB.w * wWe[3][j] + qeB * wWe[4][j];
        v1 = (v1 > 0.f) ? v1 : 0.2f * v1;
        lg1 += v1 * wAtt[j];
      }
      lg0 += __shfl_xor(lg0, 1); lg1 += __shfl_xor(lg1, 1);
      lg0 += __shfl_xor(lg0, 2); lg1 += __shfl_xor(lg1, 2);
      lg0 += __shfl_xor(lg0, 4); lg1 += __shfl_xor(lg1, 4);
      lg0 += __shfl_xor(lg0, 8); lg1 += __shfl_xor(lg1, 8);
      lg1 = (i + 1 < e1) ? lg1 : -INFINITY;
      {
        float nm = fmaxf(m, fmaxf(lg0, lg1));
        float sc = __expf(m - nm);
        float p0 = __expf(lg0 - nm);
        float p1 = __expf(lg1 - nm);
        dsum = dsum * sc + p0 + p1;
#pragma unroll
        for (int j = 0; j < 8; ++j)
          acc[j] = fmaf(p1, x1[j], fmaf(p0, x0[j], acc[j] * sc));
        m = nm;
      }

      // ===== stage 2: edges i+2, i+3 =====
      float x2[8], x3[8];
#pragma unroll
      for (int j = 0; j < 8; ++j) { x2[j] = bf2f(uC[j]); x3[j] = bf2f(uD[j]); }
      uC = *(const us8*)&xlr[(size_t)sN2 * 1024 + base];   // payload i+6
      uD = *(const us8*)&xlr[(size_t)sN3 * 1024 + base];   // payload i+7
      int j4b = (i + 4 < e1) ? i + 4 : last;
      int j5b = (i + 5 < e1) ? i + 5 : last;
      qaA = ea4[j4b]; qeA = ea1[j4b];                      // attrs for next iter stage 1
      qaB = ea4[j5b]; qeB = ea1[j5b];
      int j8 = (i + 8 < e1) ? i + 8 : last;
      int j9 = (i + 9 < e1) ? i + 9 : last;
      sN0 = esrc[j8]; sN1 = esrc[j9];

      float lg2 = 0.f, lg3 = 0.f;
#pragma unroll
      for (int j = 0; j < 8; ++j) {
        float v2 = x2[j] + xr_reg[j] + qaC.x * wWe[0][j] + qaC.y * wWe[1][j]
                 + qaC.z * wWe[2][j] + qaC.w * wWe[3][j] + qeC * wWe[4][j];
        v2 = (v2 > 0.f) ? v2 : 0.2f * v2;
        lg2 += v2 * wAtt[j];
        float v3 = x3[j] + xr_reg[j] + qaD.x * wWe[0][j] + qaD.y * wWe[1][j]
                 + qaD.z * wWe[2][j] + qaD.w * wWe[3][j] + qeD * wWe[4][j];
        v3 = (v3 > 0.f) ? v3 : 0.2f * v3;
        lg3 += v3 * wAtt[j];
      }
      lg2 += __shfl_xor(lg2, 1); lg3 += __shfl_xor(lg3, 1);
      lg2 += __shfl_xor(lg2, 2); lg3 += __shfl_xor(lg3, 2);
      lg2 += __shfl_xor(lg2, 4); lg3 += __shfl_xor(lg3, 4);
      lg2 += __shfl_xor(lg2, 8); lg3 += __shfl_xor(lg3, 8);
      lg2 = (i + 2 < e1) ? lg2 : -INFINITY;
      lg3 = (i + 3 < e1) ? lg3 : -INFINITY;
      {
        float nm = fmaxf(m, fmaxf(lg2, lg3));
        float sc = __expf(m - nm);
        float p2 = __expf(lg2 - nm);
        float p3 = __expf(lg3 - nm);
        dsum = dsum * sc + p2 + p3;
#pragma unroll
        for (int j = 0; j < 8; ++j)
          acc[j] = fmaf(p3, x3[j], fmaf(p2, x2[j], acc[j] * sc));
        m = nm;
      }
    }
  }

  // normalize per head, head-average via shfl, fused bias/relu/residual/LN
  float inv = (dsum > 0.f) ? (1.f / dsum) : 0.f;
  int c8 = (lane & 15) * 8;
  float o[8];
  float s1 = 0.f, s2 = 0.f;
#pragma unroll
  for (int j = 0; j < 8; ++j) {
    float v = acc[j] * inv;
    v += __shfl_xor(v, 16);
    v += __shfl_xor(v, 32);
    float oo = 0.25f * v + gbias[c8 + j];
    oo = fmaxf(oo, 0.f);
    oo += h_in[(size_t)n * 128 + c8 + j];
    o[j] = oo;
    s1 += oo; s2 += oo * oo;
  }
  s1 += __shfl_xor(s1, 1);  s2 += __shfl_xor(s2, 1);
  s1 += __shfl_xor(s1, 2);  s2 += __shfl_xor(s2, 2);
  s1 += __shfl_xor(s1, 4);  s2 += __shfl_xor(s2, 4);
  s1 += __shfl_xor(s1, 8);  s2 += __shfl_xor(s2, 8);
  s1 += __shfl_xor(s1, 16); s2 += __shfl_xor(s2, 16);
  s1 += __shfl_xor(s1, 32); s2 += __shfl_xor(s2, 32);
  float mean = s1 * (1.f / 512.f);
  float var = s2 * (1.f / 512.f) - mean * mean;
  float rs = rsqrtf(var + 1e-5f);
  if (lane < 16) {
#pragma unroll
    for (int j = 0; j < 8; ++j) {
      float val = (o[j] - mean) * rs * lng[c8 + j] + lnb[c8 + j];
      h_out[(size_t)n * 128 + c8 + j] = val;
      hbf_out[(size_t)n * 128 + c8 + j] = f2bf(val);
    }
  }
}

// ---------------- social pool edge kernel: fused weights + LDS-merged scatter ------
// 512 thr = 8 waves; wave w owns output cols 16w..16w+15. All MFMAs upfront, then
// gated -> gT (stride-65 fp32, overlays dead sT), then 32-row segmented scan.
__global__ __launch_bounds__(512) void sp_edge_kernel(
    const unsigned short* __restrict__ sab, const float* __restrict__ b1,
    const unsigned short* __restrict__ W2T, const float* __restrict__ b2,
    const unsigned short* __restrict__ FT, const float* __restrict__ gbF,
    const int* __restrict__ ei, const int* __restrict__ eidS,
    float* __restrict__ pool)
{
  __shared__ __align__(16) float gT[128 * 65];            // 33.3KB; first 16KB doubles as sT
  __shared__ int rsrc[64];
  __shared__ int rdst[64];
  unsigned short* sT = (unsigned short*)gT;
  int tid = threadIdx.x;
  int w = tid >> 6, lane = tid & 63;
  int l15 = lane & 15, q = lane >> 4;
  int col = w * 16 + l15;

  // tile-invariant B fragments in registers (both GEMMs)
  short8 bW[4], bF[4];
#pragma unroll
  for (int ks = 0; ks < 4; ++ks) {
    bW[ks] = *(const short8*)&W2T[(size_t)col * 128 + (ks * 4 + q) * 8];
    bF[ks] = *(const short8*)&FT [(size_t)col * 128 + (ks * 4 + q) * 8];
  }
  float b2c = b2[col];
  float gbc = gbF[col];

  int ebase = blockIdx.x * 64;          // 5000*64 == N_EDGES exactly: no partial tiles
  if (tid < 64) {
    int e = eidS[ebase + tid];
    rsrc[tid] = ei[e];
    rdst[tid] = ei[N_EDGES + e];
  }
  __syncthreads();

  // build T tile: 1024 chunks / 512 threads
#pragma unroll
  for (int i = 0; i < 2; ++i) {
    int ch = tid + i * 512;
    int r = ch >> 4, kc = ch & 15, c0 = kc * 8;
    int s = rsrc[r], d = rdst[r];
    us8 ua = *(const us8*)&sab[(size_t)s * 256 + c0];
    us8 ub = *(const us8*)&sab[(size_t)d * 256 + 128 + c0];
    float4 bb0 = *(const float4*)&b1[c0];
    float4 bb1 = *(const float4*)&b1[c0 + 4];
    float bv[8] = {bb0.x, bb0.y, bb0.z, bb0.w, bb1.x, bb1.y, bb1.z, bb1.w};
    short8 o;
#pragma unroll
    for (int j = 0; j < 8; ++j)
      o[j] = (short)f2bf(fmaxf(bf2f(ua[j]) + bf2f(ub[j]) + bv[j], 0.f));
    *(short8*)&sT[r * 128 + ((kc ^ (r & 7)) * 8)] = o;
  }
  __syncthreads();

  // all MFMAs first (both GEMMs share A fragments)
  f32x4 acc1[4], acc2[4];
#pragma unroll
  for (int rg = 0; rg < 4; ++rg) {
    int mr = rg * 16 + l15;
    acc1[rg] = (f32x4){0, 0, 0, 0};
    acc2[rg] = (f32x4){0, 0, 0, 0};
#pragma unroll
    for (int ks = 0; ks < 4; ++ks) {
      short8 a = *(const short8*)&sT[mr * 128 + (((ks * 4 + q) ^ (mr & 7)) * 8)];
      acc1[rg] = __builtin_amdgcn_mfma_f32_16x16x32_bf16(a, bW[ks], acc1[rg], 0, 0, 0);
      acc2[rg] = __builtin_amdgcn_mfma_f32_16x16x32_bf16(a, bF[ks], acc2[rg], 0, 0, 0);
    }
  }
  __syncthreads();   // all sT reads done before gT overwrites it

  // gate in registers, write gated to gT[col][row] (stride 65: conflict-free)
#pragma unroll
  for (int rg = 0; rg < 4; ++rg) {
    int rb = rg * 16 + 4 * q;
#pragma unroll
    for (int r = 0; r < 4; ++r) {
      float inter = acc1[rg][r] + b2c;
      float gg = acc2[rg][r] + gbc;
      gT[col * 65 + rb + r] = inter * (1.f / (1.f + __expf(-gg)));
    }
  }
  __syncthreads();

  // segmented scan by src: 256 threads, 2 halves x 32 rows (rows are src-sorted)
  if (tid < 256) {
    int c = tid & 127, half = tid >> 7;
    int rbeg = half * 32, rend = rbeg + 32;
    int curs = -1; float run = 0.f;
    for (int r = rbeg; r < rend; ++r) {
      int s = rsrc[r];
      if (s != curs) {
        if (curs >= 0) atomAddF(&pool[(size_t)curs * 128 + c], run);
        curs = s; run = 0.f;
      }
      run += gT[c * 65 + r];
    }
    atomAddF(&pool[(size_t)curs * 128 + c], run);
  }
}

// ---------------- finalize: out = LN(h + pool/max(cnt,1)) ----------------
__global__ __launch_bounds__(256) void finalize_kernel(
    const float* __restrict__ h, const float* __restrict__ pool,
    const int* __restrict__ degS, const float* __restrict__ g,
    const float* __restrict__ b, float* __restrict__ out)
{
  int t = blockIdx.x * 256 + threadIdx.x;
  int n = t >> 6, lane = t & 63;
  if (n >= N_NODES) return;
  float cnt = fmaxf((float)degS[n], 1.f);
  float a = h[(size_t)n * 128 + lane] + pool[(size_t)n * 128 + lane] / cnt;
  float c2 = h[(size_t)n * 128 + 64 + lane] + pool[(size_t)n * 128 + 64 + lane] / cnt;
  float s = a + c2, s2 = a * a + c2 * c2;
#pragma unroll
  for (int o = 1; o < 64; o <<= 1) { s += __shfl_xor(s, o); s2 += __shfl_xor(s2, o); }
  float mean = s * (1.f / 128.f);
  float var = s2 * (1.f / 128.f) - mean * mean;
  float rs = rsqrtf(var + 1e-5f);
  out[(size_t)n * 128 + lane] = (a - mean) * rs * g[lane] + b[lane];
  out[(size_t)n * 128 + 64 + lane] = (c2 - mean) * rs * g[64 + lane] + b[64 + lane];
}

// ---------------- host ----------------
extern "C" void kernel_launch(void* const* d_in, const int* in_sizes, int n_in,
                              void* d_out, int out_size, void* d_ws, size_t ws_size,
                              hipStream_t stream) {
  (void)in_sizes; (void)n_in; (void)out_size; (void)ws_size;
  const float* x     = (const float*)d_in[0];
  const int*   ei    = (const int*)d_in[1];
  const float* eattr = (const float*)d_in[2];
  const float* embW  = (const float*)d_in[3];
  const float* embB  = (const float*)d_in[4];
  const float* gWl   = (const float*)d_in[5];
  const float* gWr   = (const float*)d_in[6];
  const float* gWe   = (const float*)d_in[7];
  const float* gAtt  = (const float*)d_in[8];
  const float* gB    = (const float*)d_in[9];
  const float* lnG   = (const float*)d_in[10];
  const float* lnB   = (const float*)d_in[11];
  const float* spW1  = (const float*)d_in[12];
  const float* spB1  = (const float*)d_in[13];
  const float* spW2  = (const float*)d_in[14];
  const float* spB2  = (const float*)d_in[15];
  const float* spGW  = (const float*)d_in[16];
  const float* spGB  = (const float*)d_in[17];
  const float* fnG   = (const float*)d_in[18];
  const float* fnB   = (const float*)d_in[19];
  float* out = (float*)d_out;

  char* ws = (char*)d_ws;
  size_t off = 0;
  auto alloc = [&](size_t bytes) {
    void* p = ws + off;
    off = (off + bytes + 255) & ~(size_t)255;
    return p;
  };
  float* hA   = (float*)alloc((size_t)N_NODES * 128 * 4);
  float* hB   = (float*)alloc((size_t)N_NODES * 128 * 4);
  unsigned short* hbfA = (unsigned short*)alloc((size_t)N_NODES * 128 * 2);
  unsigned short* hbfB = (unsigned short*)alloc((size_t)N_NODES * 128 * 2);
  unsigned short* xlr  = (unsigned short*)alloc((size_t)N_NODES * 1024 * 2);
  unsigned short* sab  = (unsigned short*)alloc((size_t)N_NODES * 256 * 2);
  float* pool = (float*)alloc((size_t)N_NODES * 128 * 4);
  unsigned short* WlrT = (unsigned short*)alloc((size_t)4 * 1024 * 128 * 2);
  unsigned short* W1T  = (unsigned short*)alloc((size_t)256 * 128 * 2);
  unsigned short* W2T  = (unsigned short*)alloc((size_t)128 * 128 * 2);
  unsigned short* gWT  = (unsigned short*)alloc((size_t)128 * 128 * 2);
  unsigned short* W2bf = (unsigned short*)alloc((size_t)128 * 128 * 2);
  unsigned short* FT   = (unsigned short*)alloc((size_t)128 * 128 * 2);
  float* gbF = (float*)alloc((size_t)128 * 4);
  int* degD = (int*)alloc((size_t)N_NODES * 4);
  int* degS = (int*)alloc((size_t)N_NODES * 4);
  int* offD = (int*)alloc((size_t)(N_NODES + 1) * 4);
  int* offS = (int*)alloc((size_t)(N_NODES + 1) * 4);
  int* curD = (int*)alloc((size_t)N_NODES * 4);
  int* curS = (int*)alloc((size_t)N_NODES * 4);
  int* eidD = (int*)alloc((size_t)N_EDGES * 4);
  int* eidS = (int*)alloc((size_t)N_EDGES * 4);
  int* esrc = (int*)alloc((size_t)N_EDGES * 4);
  float4* ea4 = (float4*)alloc((size_t)N_EDGES * 16);
  float* ea1 = (float*)alloc((size_t)N_EDGES * 4);

  hipMemsetAsync(degD, 0, (size_t)N_NODES * 4, stream);
  hipMemsetAsync(degS, 0, (size_t)N_NODES * 4, stream);
  hipMemsetAsync(pool, 0, (size_t)N_NODES * 128 * 4, stream);

  pack_kernel<<<(606208 + 255) / 256, 256, 0, stream>>>(gWl, gWr, spW1, spW2, spGW,
                                                        WlrT, W1T, W2T, gWT, W2bf);
  // F^T = (W2 @ gW)^T  via  C[n][k] = sum_j gWT[n][j] * W2bf[k][j]
  mfma_gemm_kernel<<<dim3(2, 2), 256, 0, stream>>>(gWT, W2bf, FT, 128, 128);
  fuse_bias_kernel<<<1, 128, 0, stream>>>(spB2, spGW, spGB, gbF);

  embed_kernel<<<(N_NODES * 128) / 256, 256, 0, stream>>>(x, embW, embB, hA, hbfA);
  hist_kernel<<<(N_EDGES + 255) / 256, 256, 0, stream>>>(ei, degD, degS);
  scan_kernel<<<1, 1024, 0, stream>>>(degD, offD, curD, degS, offS, curS, N_NODES);
  scatter_kernel<<<(N_EDGES + 255) / 256, 256, 0, stream>>>(ei, curD, curS, eidD, eidS);
  reorder_kernel<<<(N_EDGES + 255) / 256, 256, 0, stream>>>(ei, eattr, eidD, esrc, ea4, ea1);

  const int MB64 = (N_NODES + 63) / 64;   // 157
  float* hcur = hA; float* hnext = hB;
  unsigned short* hbcur = hbfA; unsigned short* hbnext = hbfB;
  for (int l = 0; l < LAYERS; ++l) {
    mfma_gemm_kernel<<<dim3(16, MB64), 256, 0, stream>>>(
        hbcur, WlrT + (size_t)l * 1024 * 128, xlr, N_NODES, 1024);
    gat_agg_kernel<<<(N_NODES + 3) / 4, 256, 0, stream>>>(hcur, hnext, hbnext, xlr,
                                                          esrc, ea4, ea1, offD,
                                                          gWe + (size_t)l * EDIM * HC,
                                                          gAtt + (size_t)l * HC,
                                                          gB + (size_t)l * 128,
                                                          lnG + (size_t)l * 128,
                                                          lnB + (size_t)l * 128);
    float* t1 = hcur; hcur = hnext; hnext = t1;
    unsigned short* t2 = hbcur; hbcur = hbnext; hbnext = t2;
  }
  mfma_gemm_kernel<<<dim3(4, MB64), 256, 0, stream>>>(hbcur, W1T, sab, N_NODES, 256);
  sp_edge_kernel<<<N_EDGES / 64, 512, 0, stream>>>(sab, spB1, W2T, spB2, FT, gbF,
                                                   ei, eidS, pool);
  finalize_kernel<<<(N_NODES + 3) / 4, 256, 0, stream>>>(hcur, pool, degS, fnG, fnB, out);
}